// Round 1
// baseline (126.304 us; speedup 1.0000x reference)
//
#include <hip/hip_runtime.h>
#include <math.h>

// Problem constants (match reference)
constexpr int P  = 2;
constexpr int B  = 96;
constexpr int A  = 32;
constexpr int NT = 24;
constexpr int N  = B * A;      // 3072
constexpr int MD = 4;
constexpr int MA = 4;
constexpr int NPOL = MD + MA;  // 8
constexpr float C_LK = 0.0897935610625833f;

__global__ void zero_out_kernel(float* out) {
    int t = threadIdx.x;
    if (t < 2 * P) out[t] = 0.0f;
}

struct Polar {
    float xp[3];
    float ri, dgi, lami;
    float w0[3];
    float w1[3];
    int   wm0, wm1;
    int   valid;
    int   a_i;
    int   bti;
};

__global__ __launch_bounds__(256) void lkball_kernel(
    const float* __restrict__ pose_coords,    // P*N*3
    const int*   __restrict__ block_type,     // P*B
    const int*   __restrict__ min_sep,        // P*B*B
    const int*   __restrict__ all_bonds,      // NT*A*2
    const int*   __restrict__ bond_ranges,    // NT*A*2
    const int*   __restrict__ n_donH,         // NT
    const int*   __restrict__ n_acc,          // NT
    const int*   __restrict__ donH_inds,      // NT*MD
    const int*   __restrict__ don_hvy_inds,   // NT*MD
    const int*   __restrict__ acc_inds,       // NT*MA
    const int*   __restrict__ hyb,            // NT*MA
    const int*   __restrict__ is_h,           // NT*A
    const float* __restrict__ lk_params,      // NT*A*4
    const int*   __restrict__ path_dist,      // NT*A*A
    const float* __restrict__ glob,           // cutoff, ramp2, d2_low
    const float* __restrict__ wglob,          // wdist, wang
    const float* __restrict__ sp2t,           // 2
    const float* __restrict__ sp3t,           // 2
    const float* __restrict__ ringt,          // 2
    float*       __restrict__ out)            // 2*P
{
    __shared__ Polar sp;
    __shared__ int   spath[A];
    __shared__ int   smsep[B];
    __shared__ float red0[4], red1[4];

    const int bid = blockIdx.x;
    const int p   = bid / (B * NPOL);
    const int rem = bid % (B * NPOL);
    const int b   = rem / NPOL;
    const int k   = rem % NPOL;
    const int tid = threadIdx.x;

    if (tid == 0) {
        const int bt = block_type[p * B + b];
        sp.bti = bt;
        const float wdist = wglob[0];
        const float wang  = wglob[1];

        if (k < MD) {
            // ---- donor polar ----
            const int nd  = n_donH[bt];
            sp.valid = (k < nd) ? 1 : 0;
            const int hvy = don_hvy_inds[bt * MD + k];
            const int Hi  = donH_inds[bt * MD + k];
            sp.a_i = hvy;
            const float* hc = pose_coords + (size_t)(p * N + b * A + hvy) * 3;
            const float* Hc = pose_coords + (size_t)(p * N + b * A + Hi) * 3;
            float dx = Hc[0] - hc[0], dy = Hc[1] - hc[1], dz = Hc[2] - hc[2];
            float inv = 1.0f / sqrtf(dx * dx + dy * dy + dz * dz + 1e-12f);
            sp.xp[0] = hc[0]; sp.xp[1] = hc[1]; sp.xp[2] = hc[2];
            sp.w0[0] = hc[0] + wdist * dx * inv;
            sp.w0[1] = hc[1] + wdist * dy * inv;
            sp.w0[2] = hc[2] + wdist * dz * inv;
            sp.w1[0] = 0.f; sp.w1[1] = 0.f; sp.w1[2] = 0.f;
            sp.wm0 = sp.valid;
            sp.wm1 = 0;
        } else {
            // ---- acceptor polar ----
            const int kk = k - MD;
            const int na = n_acc[bt];
            sp.valid = (kk < na) ? 1 : 0;
            const int ai = acc_inds[bt * MA + kk];
            sp.a_i = ai;
            const int r0    = bond_ranges[(bt * A + ai) * 2 + 0];
            const int base  = all_bonds[(bt * A + r0) * 2 + 1];
            const int r0b   = bond_ranges[(bt * A + base) * 2 + 0];
            const int base2 = all_bonds[(bt * A + r0b) * 2 + 1];
            const float* c  = pose_coords + (size_t)(p * N + b * A + ai)    * 3;
            const float* bx = pose_coords + (size_t)(p * N + b * A + base)  * 3;
            const float* ax = pose_coords + (size_t)(p * N + b * A + base2) * 3;

            float e1x = c[0] - bx[0], e1y = c[1] - bx[1], e1z = c[2] - bx[2];
            float inv1 = 1.0f / sqrtf(e1x * e1x + e1y * e1y + e1z * e1z + 1e-12f);
            e1x *= inv1; e1y *= inv1; e1z *= inv1;

            float ux = bx[0] - ax[0], uy = bx[1] - ax[1], uz = bx[2] - ax[2];
            // cross(u, e1)
            float nx = uy * e1z - uz * e1y;
            float ny = uz * e1x - ux * e1z;
            float nz = ux * e1y - uy * e1x;
            float inv2 = 1.0f / sqrtf(nx * nx + ny * ny + nz * nz + 1e-12f);
            nx *= inv2; ny *= inv2; nz *= inv2;
            // e2 = cross(nrm, e1)
            float e2x = ny * e1z - nz * e1y;
            float e2y = nz * e1x - nx * e1z;
            float e2z = nx * e1y - ny * e1x;

            const int hy = hyb[bt * MA + kk];
            const float* tab = (hy == 0) ? sp2t : ((hy == 1) ? sp3t : ringt);
            const float ct = cosf(wang), st = sinf(wang);

            float chi0 = tab[0], chi1 = tab[1];
            float c0 = cosf(chi0), s0c = sinf(chi0);
            float c1 = cosf(chi1), s1c = sinf(chi1);

            sp.w0[0] = c[0] - wdist * ct * e1x + wdist * st * c0 * e2x + wdist * st * s0c * nx;
            sp.w0[1] = c[1] - wdist * ct * e1y + wdist * st * c0 * e2y + wdist * st * s0c * ny;
            sp.w0[2] = c[2] - wdist * ct * e1z + wdist * st * c0 * e2z + wdist * st * s0c * nz;
            sp.w1[0] = c[0] - wdist * ct * e1x + wdist * st * c1 * e2x + wdist * st * s1c * nx;
            sp.w1[1] = c[1] - wdist * ct * e1y + wdist * st * c1 * e2y + wdist * st * s1c * ny;
            sp.w1[2] = c[2] - wdist * ct * e1z + wdist * st * c1 * e2z + wdist * st * s1c * nz;
            sp.wm0 = sp.valid;
            sp.wm1 = sp.valid;
            sp.xp[0] = c[0]; sp.xp[1] = c[1]; sp.xp[2] = c[2];
        }
        const float* pr = lk_params + (size_t)(bt * A + sp.a_i) * 4;
        sp.ri   = pr[0];
        sp.dgi  = pr[1];
        sp.lami = pr[2];
    }
    __syncthreads();

    if (!sp.valid) return;  // uniform across block; no contribution to either sum

    // Cache separation rows in LDS
    if (tid < A)  spath[tid] = path_dist[(sp.bti * A + sp.a_i) * A + tid];
    if (tid >= 64 && tid < 64 + B) smsep[tid - 64] = min_sep[(p * B + b) * B + (tid - 64)];
    __syncthreads();

    // Pull polar data into registers (LDS broadcast)
    const float xpx = sp.xp[0], xpy = sp.xp[1], xpz = sp.xp[2];
    const float ri = sp.ri, dgi = sp.dgi;
    const float inv_lam = 1.0f / sp.lami;
    const float w0x = sp.w0[0], w0y = sp.w0[1], w0z = sp.w0[2];
    const float w1x = sp.w1[0], w1y = sp.w1[1], w1z = sp.w1[2];
    const int wm0 = sp.wm0, wm1 = sp.wm1;
    const float cutoff = glob[0], ramp2 = glob[1], d2_low = glob[2];
    const float inv_ramp2 = 1.0f / ramp2;
    const float pref = C_LK * dgi * inv_lam;

    float acc0 = 0.0f, acc1 = 0.0f;

    for (int j = tid; j < N; j += 256) {
        const int b_j = j >> 5;        // j / A
        const int a_j = j & (A - 1);   // j % A
        const float* cj = pose_coords + (size_t)(p * N + j) * 3;
        const float cjx = cj[0], cjy = cj[1], cjz = cj[2];

        const float dx = xpx - cjx, dy = xpy - cjy, dz = xpz - cjz;
        float d2 = dx * dx + dy * dy + dz * dz;
        d2 = fmaxf(d2, 0.01f);
        const float d = sqrtf(d2);

        const int sep = (b_j == b) ? spath[a_j] : smsep[b_j];
        if (sep < 4 || d >= cutoff) continue;

        const int bt_j = block_type[p * B + b_j];
        if (is_h[bt_j * A + a_j] != 0) continue;  // hydrogens excluded

        const float rj   = lk_params[(size_t)(bt_j * A + a_j) * 4 + 0];
        const float volj = lk_params[(size_t)(bt_j * A + a_j) * 4 + 3];

        const float x  = (d - (ri + rj)) * inv_lam;
        const float lk = pref * volj * __expf(-x * x) / d2;

        // water weighting
        float d0x = w0x - cjx, d0y = w0y - cjy, d0z = w0z - cjz;
        float d1x = w1x - cjx, d1y = w1y - cjy, d1z = w1z - cjz;
        float d2w0 = wm0 ? (d0x * d0x + d0y * d0y + d0z * d0z) : 1e9f;
        float d2w1 = wm1 ? (d1x * d1x + d1y * d1y + d1z * d1z) : 1e9f;
        float d2wmin = fminf(d2w0, d2w1);
        float wt = (d2_low + ramp2 - d2wmin) * inv_ramp2;
        wt = fminf(fmaxf(wt, 0.0f), 1.0f);
        const float frac = wt * wt * (3.0f - 2.0f * wt);

        acc0 += lk;
        acc1 += lk * frac;
    }

    // wave reduce (64 lanes)
    for (int off = 32; off > 0; off >>= 1) {
        acc0 += __shfl_down(acc0, off);
        acc1 += __shfl_down(acc1, off);
    }
    const int wave = tid >> 6;
    const int lane = tid & 63;
    if (lane == 0) { red0[wave] = acc0; red1[wave] = acc1; }
    __syncthreads();
    if (tid == 0) {
        float t0 = red0[0] + red0[1] + red0[2] + red0[3];
        float t1 = red1[0] + red1[1] + red1[2] + red1[3];
        atomicAdd(&out[p], t0);
        atomicAdd(&out[P + p], t1);
    }
}

extern "C" void kernel_launch(void* const* d_in, const int* in_sizes, int n_in,
                              void* d_out, int out_size, void* d_ws, size_t ws_size,
                              hipStream_t stream) {
    const float* pose_coords  = (const float*)d_in[0];
    const int*   block_type   = (const int*)  d_in[1];
    const int*   min_sep      = (const int*)  d_in[2];
    // d_in[3] = bt_n_atoms (unused: all blocks have A atoms)
    const int*   all_bonds    = (const int*)  d_in[4];
    const int*   bond_ranges  = (const int*)  d_in[5];
    const int*   n_donH       = (const int*)  d_in[6];
    const int*   n_acc        = (const int*)  d_in[7];
    const int*   donH_inds    = (const int*)  d_in[8];
    const int*   don_hvy_inds = (const int*)  d_in[9];
    const int*   acc_inds     = (const int*)  d_in[10];
    const int*   hyb          = (const int*)  d_in[11];
    const int*   is_h         = (const int*)  d_in[12];
    const float* lk_params    = (const float*)d_in[13];
    const int*   path_dist    = (const int*)  d_in[14];
    const float* glob         = (const float*)d_in[15];
    const float* wglob        = (const float*)d_in[16];
    const float* sp2t         = (const float*)d_in[17];
    const float* sp3t         = (const float*)d_in[18];
    const float* ringt        = (const float*)d_in[19];
    float* out = (float*)d_out;

    zero_out_kernel<<<1, 64, 0, stream>>>(out);

    const int nblocks = P * B * NPOL;  // 1536
    lkball_kernel<<<nblocks, 256, 0, stream>>>(
        pose_coords, block_type, min_sep, all_bonds, bond_ranges,
        n_donH, n_acc, donH_inds, don_hvy_inds, acc_inds, hyb, is_h,
        lk_params, path_dist, glob, wglob, sp2t, sp3t, ringt, out);
}

// Round 2
// 109.811 us; speedup vs baseline: 1.1502x; 1.1502x over previous
//
#include <hip/hip_runtime.h>
#include <math.h>

// Problem constants (match reference)
constexpr int P  = 2;
constexpr int B  = 96;
constexpr int A  = 32;
constexpr int N  = B * A;      // 3072
constexpr int MD = 4;
constexpr int MA = 4;
constexpr int NPOL = MD + MA;  // 8
constexpr int SJ = 2;          // j-slices per (p,b); grid = P*B*SJ = 384
constexpr int JS = N / SJ;     // 1536 atoms per slice
constexpr int JPT = JS / 256;  // 6 j-atoms per thread
constexpr float C_LK = 0.0897935610625833f;

__global__ void zero_out_kernel(float* out) {
    int t = threadIdx.x;
    if (t < 2 * P) out[t] = 0.0f;
}

// polar LDS layout: 16 floats per polar
// [0..2] xp  [3..5] w0  [6..8] w1  [9] ri  [10] pref (0 if invalid)  [11] inv_lam
__global__ __launch_bounds__(256) void lkball_kernel(
    const float* __restrict__ pose_coords,    // P*N*3
    const int*   __restrict__ block_type,     // P*B
    const int*   __restrict__ min_sep,        // P*B*B
    const int*   __restrict__ all_bonds,      // NT*A*2
    const int*   __restrict__ bond_ranges,    // NT*A*2
    const int*   __restrict__ n_donH,         // NT
    const int*   __restrict__ n_acc,          // NT
    const int*   __restrict__ donH_inds,      // NT*MD
    const int*   __restrict__ don_hvy_inds,   // NT*MD
    const int*   __restrict__ acc_inds,       // NT*MA
    const int*   __restrict__ hyb,            // NT*MA
    const int*   __restrict__ is_h,           // NT*A
    const float* __restrict__ lk_params,      // NT*A*4
    const int*   __restrict__ path_dist,      // NT*A*A
    const float* __restrict__ glob,           // cutoff, ramp2, d2_low
    const float* __restrict__ wglob,          // wdist, wang
    const float* __restrict__ sp2t,
    const float* __restrict__ sp3t,
    const float* __restrict__ ringt,
    float*       __restrict__ out)            // 2*P
{
    __shared__ float spolar[NPOL][16];
    __shared__ int   spolai[NPOL];
    __shared__ int   s_bt[B];
    __shared__ int   smsep[B];
    __shared__ int   spath[NPOL * A];
    __shared__ float red0[4], red1[4];

    const int bid   = blockIdx.x;
    const int p     = bid / (B * SJ);
    const int rem   = bid % (B * SJ);
    const int b     = rem / SJ;
    const int slice = rem % SJ;
    const int tid   = threadIdx.x;

    // ---- Phase 1: polar setup (lanes 0..7), bt row (64..159), msep row (160..255)
    if (tid < NPOL) {
        const int k  = tid;
        const int bt = block_type[p * B + b];
        const float wdist = wglob[0];
        const float wang  = wglob[1];
        float xp[3], w0[3], w1[3];
        int   a_i, valid;
        if (k < MD) {
            valid = (k < n_donH[bt]) ? 1 : 0;
            const int hvy = don_hvy_inds[bt * MD + k];
            const int Hi  = donH_inds[bt * MD + k];
            a_i = hvy;
            const float* hc = pose_coords + (size_t)(p * N + b * A + hvy) * 3;
            const float* Hc = pose_coords + (size_t)(p * N + b * A + Hi) * 3;
            float dx = Hc[0] - hc[0], dy = Hc[1] - hc[1], dz = Hc[2] - hc[2];
            float inv = 1.0f / sqrtf(dx * dx + dy * dy + dz * dz + 1e-12f);
            xp[0] = hc[0]; xp[1] = hc[1]; xp[2] = hc[2];
            w0[0] = hc[0] + wdist * dx * inv;
            w0[1] = hc[1] + wdist * dy * inv;
            w0[2] = hc[2] + wdist * dz * inv;
            // donor's second water is always masked: park it far away
            w1[0] = hc[0] + 1.0e3f; w1[1] = hc[1] + 1.0e3f; w1[2] = hc[2] + 1.0e3f;
        } else {
            const int kk = k - MD;
            valid = (kk < n_acc[bt]) ? 1 : 0;
            const int ai = acc_inds[bt * MA + kk];
            a_i = ai;
            const int r0    = bond_ranges[(bt * A + ai) * 2 + 0];
            const int base  = all_bonds[(bt * A + r0) * 2 + 1];
            const int r0b   = bond_ranges[(bt * A + base) * 2 + 0];
            const int base2 = all_bonds[(bt * A + r0b) * 2 + 1];
            const float* c  = pose_coords + (size_t)(p * N + b * A + ai)    * 3;
            const float* bx = pose_coords + (size_t)(p * N + b * A + base)  * 3;
            const float* ax = pose_coords + (size_t)(p * N + b * A + base2) * 3;

            float e1x = c[0] - bx[0], e1y = c[1] - bx[1], e1z = c[2] - bx[2];
            float inv1 = 1.0f / sqrtf(e1x * e1x + e1y * e1y + e1z * e1z + 1e-12f);
            e1x *= inv1; e1y *= inv1; e1z *= inv1;

            float ux = bx[0] - ax[0], uy = bx[1] - ax[1], uz = bx[2] - ax[2];
            float nx = uy * e1z - uz * e1y;
            float ny = uz * e1x - ux * e1z;
            float nz = ux * e1y - uy * e1x;
            float inv2 = 1.0f / sqrtf(nx * nx + ny * ny + nz * nz + 1e-12f);
            nx *= inv2; ny *= inv2; nz *= inv2;
            float e2x = ny * e1z - nz * e1y;
            float e2y = nz * e1x - nx * e1z;
            float e2z = nx * e1y - ny * e1x;

            const int hy = hyb[bt * MA + kk];
            const float* tab = (hy == 0) ? sp2t : ((hy == 1) ? sp3t : ringt);
            const float ct = cosf(wang), st = sinf(wang);
            float c0 = cosf(tab[0]), s0 = sinf(tab[0]);
            float c1 = cosf(tab[1]), s1 = sinf(tab[1]);

            xp[0] = c[0]; xp[1] = c[1]; xp[2] = c[2];
            w0[0] = c[0] - wdist * ct * e1x + wdist * st * c0 * e2x + wdist * st * s0 * nx;
            w0[1] = c[1] - wdist * ct * e1y + wdist * st * c0 * e2y + wdist * st * s0 * ny;
            w0[2] = c[2] - wdist * ct * e1z + wdist * st * c0 * e2z + wdist * st * s0 * nz;
            w1[0] = c[0] - wdist * ct * e1x + wdist * st * c1 * e2x + wdist * st * s1 * nx;
            w1[1] = c[1] - wdist * ct * e1y + wdist * st * c1 * e2y + wdist * st * s1 * ny;
            w1[2] = c[2] - wdist * ct * e1z + wdist * st * c1 * e2z + wdist * st * s1 * nz;
        }
        const float* pr = lk_params + (size_t)(bt * A + a_i) * 4;
        const float lam = pr[2];
        spolar[k][0] = xp[0]; spolar[k][1] = xp[1]; spolar[k][2] = xp[2];
        spolar[k][3] = w0[0]; spolar[k][4] = w0[1]; spolar[k][5] = w0[2];
        spolar[k][6] = w1[0]; spolar[k][7] = w1[1]; spolar[k][8] = w1[2];
        spolar[k][9]  = pr[0];
        spolar[k][10] = valid ? (C_LK * pr[1] / lam) : 0.0f;  // pref, validity folded
        spolar[k][11] = 1.0f / lam;
        spolai[k] = a_i;
    }
    if (tid >= 64 && tid < 64 + B)   s_bt[tid - 64]   = block_type[p * B + (tid - 64)];
    if (tid >= 160 && tid < 160 + B) smsep[tid - 160] = min_sep[(p * B + b) * B + (tid - 160)];
    __syncthreads();

    // ---- Phase 2: path-distance rows for all 8 polars (256 threads = 8*32)
    {
        const int k  = tid >> 5;
        const int aj = tid & 31;
        const int bt = s_bt[b];
        spath[tid] = path_dist[(bt * A + spolai[k]) * A + aj];
    }
    __syncthreads();

    // ---- Phase 3: load this thread's JPT j-atoms into registers
    const float cutoff = glob[0];
    const float inv_ramp2 = 1.0f / glob[1];
    const float c3 = glob[2] + glob[1];  // d2_low + ramp2
    const int a_j = tid & 31;            // constant across i (256 % 32 == 0)
    const int jbase = slice * JS + tid;

    float cx[JPT], cy[JPT], cz[JPT], rj[JPT], ve[JPT];
    float msep_f[JPT];
    int   intra[JPT];
#pragma unroll
    for (int i = 0; i < JPT; ++i) {
        const int j   = jbase + 256 * i;
        const int b_j = j >> 5;
        const float* cj = pose_coords + (size_t)(p * N + j) * 3;
        cx[i] = cj[0]; cy[i] = cj[1]; cz[i] = cj[2];
        const int bt_j = s_bt[b_j];
        const int hv   = is_h[bt_j * A + a_j];
        const float4 pj = *(const float4*)(lk_params + (size_t)(bt_j * A + a_j) * 4);
        rj[i] = pj.x;
        ve[i] = hv ? 0.0f : pj.w;     // heavy-mask folded into vol_j
        msep_f[i] = (float)smsep[b_j];
        intra[i]  = (b_j == b);
    }

    float acc0 = 0.0f, acc1 = 0.0f;

#pragma unroll
    for (int k = 0; k < NPOL; ++k) {
        const float px = spolar[k][0], py = spolar[k][1], pz = spolar[k][2];
        const float w0x = spolar[k][3], w0y = spolar[k][4], w0z = spolar[k][5];
        const float w1x = spolar[k][6], w1y = spolar[k][7], w1z = spolar[k][8];
        const float ri = spolar[k][9], pref = spolar[k][10], inv_lam = spolar[k][11];
        const float path_k = (float)spath[k * A + a_j];

#pragma unroll
        for (int i = 0; i < JPT; ++i) {
            const float dx = px - cx[i], dy = py - cy[i], dz = pz - cz[i];
            float d2 = fmaf(dx, dx, fmaf(dy, dy, dz * dz));
            d2 = fmaxf(d2, 0.01f);
            const float d = __builtin_amdgcn_sqrtf(d2);
            const float sep = intra[i] ? path_k : msep_f[i];
            const bool ok = (sep >= 4.0f) & (d < cutoff);

            const float x = (d - ri - rj[i]) * inv_lam;
            float lk = pref * ve[i] * __expf(-x * x) * __builtin_amdgcn_rcpf(d2);
            lk = ok ? lk : 0.0f;

            const float d0x = w0x - cx[i], d0y = w0y - cy[i], d0z = w0z - cz[i];
            const float d1x = w1x - cx[i], d1y = w1y - cy[i], d1z = w1z - cz[i];
            const float d2w0 = fmaf(d0x, d0x, fmaf(d0y, d0y, d0z * d0z));
            const float d2w1 = fmaf(d1x, d1x, fmaf(d1y, d1y, d1z * d1z));
            const float d2wmin = fminf(d2w0, d2w1);
            float wt = (c3 - d2wmin) * inv_ramp2;
            wt = fminf(fmaxf(wt, 0.0f), 1.0f);
            const float frac = wt * wt * (3.0f - 2.0f * wt);

            acc0 += lk;
            acc1 = fmaf(lk, frac, acc1);
        }
    }

    // ---- Reduce: wave shuffle -> LDS -> one atomic pair per block
    for (int off = 32; off > 0; off >>= 1) {
        acc0 += __shfl_down(acc0, off);
        acc1 += __shfl_down(acc1, off);
    }
    const int wave = tid >> 6;
    const int lane = tid & 63;
    if (lane == 0) { red0[wave] = acc0; red1[wave] = acc1; }
    __syncthreads();
    if (tid == 0) {
        atomicAdd(&out[p],     red0[0] + red0[1] + red0[2] + red0[3]);
        atomicAdd(&out[P + p], red1[0] + red1[1] + red1[2] + red1[3]);
    }
}

extern "C" void kernel_launch(void* const* d_in, const int* in_sizes, int n_in,
                              void* d_out, int out_size, void* d_ws, size_t ws_size,
                              hipStream_t stream) {
    const float* pose_coords  = (const float*)d_in[0];
    const int*   block_type   = (const int*)  d_in[1];
    const int*   min_sep      = (const int*)  d_in[2];
    const int*   all_bonds    = (const int*)  d_in[4];
    const int*   bond_ranges  = (const int*)  d_in[5];
    const int*   n_donH       = (const int*)  d_in[6];
    const int*   n_acc        = (const int*)  d_in[7];
    const int*   donH_inds    = (const int*)  d_in[8];
    const int*   don_hvy_inds = (const int*)  d_in[9];
    const int*   acc_inds     = (const int*)  d_in[10];
    const int*   hyb          = (const int*)  d_in[11];
    const int*   is_h         = (const int*)  d_in[12];
    const float* lk_params    = (const float*)d_in[13];
    const int*   path_dist    = (const int*)  d_in[14];
    const float* glob         = (const float*)d_in[15];
    const float* wglob        = (const float*)d_in[16];
    const float* sp2t         = (const float*)d_in[17];
    const float* sp3t         = (const float*)d_in[18];
    const float* ringt        = (const float*)d_in[19];
    float* out = (float*)d_out;

    zero_out_kernel<<<1, 64, 0, stream>>>(out);

    const int nblocks = P * B * SJ;  // 384
    lkball_kernel<<<nblocks, 256, 0, stream>>>(
        pose_coords, block_type, min_sep, all_bonds, bond_ranges,
        n_donH, n_acc, donH_inds, don_hvy_inds, acc_inds, hyb, is_h,
        lk_params, path_dist, glob, wglob, sp2t, sp3t, ringt, out);
}